// Round 8
// baseline (642.880 us; speedup 1.0000x reference)
//
#include <hip/hip_runtime.h>

// DSR loss: R_t = sum_i w[t,i]*x[t,i];  A_t = c*A_{t-1} + eta*R_t (c=0.99),
// B_t likewise with R^2;  D_t from (A_prev,B_prev);  out = -sum(D)/B.
//
// R10: single-pass fused kernel with decoupled lookback (rocPRIM pattern).
// Phase A = R7's proven dot pipeline (nt loads, distance-4 rotation, shfl
// pair-combine) -- at the measured ~3.5-4 TB/s streaming-read wall.  R stays
// in registers (no 8 MB R round-trip); each block publishes its 1024-row
// affine aggregate (agent-scope atomics, release flag), composes predecessor
// aggregates with the R9-k4 lookback code (tid-strided + block_scan, spin on
// flags of earlier-dispatched blocks only), replays, D-sums; the last block
// (done-counter) runs the k5 reduction verbatim (deterministic order).
// k_init zeroes flags+counter each launch (graph-capture-safe).

#define D_ETA 0.01
#define D_C   (1.0 - D_ETA)
#define D_EPS 1e-8

constexpr int BLOCK  = 256;
constexpr int CHUNK  = 1024;          // rows per block
constexpr int LPT    = CHUNK / BLOCK; // 4 rows per thread
constexpr int PASSES = CHUNK / 64;    // 16 passes of 64 rows

typedef float f32x4 __attribute__((ext_vector_type(4)));

// ---- agent-scope atomic helpers (per-XCD L2s are not coherent: G16) ----
__device__ __forceinline__ void pub_d(double* p, double v) {
    __hip_atomic_store((unsigned long long*)p, __double_as_longlong(v),
                       __ATOMIC_RELAXED, __HIP_MEMORY_SCOPE_AGENT);
}
__device__ __forceinline__ double rd_d(const double* p) {
    return __longlong_as_double(
        __hip_atomic_load((const unsigned long long*)p,
                          __ATOMIC_RELAXED, __HIP_MEMORY_SCOPE_AGENT));
}

// Hillis-Steele inclusive scan over 256 affine transforms (m, sA, sB).
__device__ __forceinline__ void block_scan(double& m, double& sA, double& sB,
                                           double* mS, double* aS, double* bS) {
    int tid = threadIdx.x;
    mS[tid] = m; aS[tid] = sA; bS[tid] = sB;
    __syncthreads();
#pragma unroll
    for (int off = 1; off < BLOCK; off <<= 1) {
        double pm = 1.0, pa = 0.0, pb = 0.0;
        if (tid >= off) { pm = mS[tid - off]; pa = aS[tid - off]; pb = bS[tid - off]; }
        __syncthreads();
        if (tid >= off) {
            sA = m * pa + sA;
            sB = m * pb + sB;
            m  = pm * m;
        }
        mS[tid] = m; aS[tid] = sA; bS[tid] = sB;
        __syncthreads();
    }
}

// ---------------- init: zero flags + done counter ----------------
__global__ __launch_bounds__(BLOCK) void k_init(int* __restrict__ flags, int n) {
    int i = blockIdx.x * BLOCK + threadIdx.x;
    if (i < n) flags[i] = 0;
}

// ---------------- fused single-pass kernel ----------------
__global__ __launch_bounds__(BLOCK, 4) void k_all(
    const float* __restrict__ w, const float* __restrict__ x, int nrows, int nb,
    double* __restrict__ aggM, double* __restrict__ aggA, double* __restrict__ aggB,
    int* __restrict__ flags, double* __restrict__ bsum, int* __restrict__ done,
    float* __restrict__ out)
{
    __shared__ double Qs[2][CHUNK];                    // 16 KB, [pair][row]
    __shared__ double mS[BLOCK], aS[BLOCK], bS[BLOCK]; // 6 KB
    __shared__ double wsum[BLOCK / 64];
    __shared__ int amLast;

    const int tid = threadIdx.x;
    const int b   = blockIdx.x;
    const long long base = (long long)b * CHUNK;
    const int q    = tid & 3;
    const int rsub = tid >> 2;
    const f32x4* w4 = (const f32x4*)w;
    const f32x4* x4 = (const f32x4*)x;

    const bool full = (base + CHUNK <= (long long)nrows);

    // ---- Phase A: dots (R7 config, untouched) ----
    if (full) {
        const long long f0 = base * 4 + tid;
        f32x4 a0 = __builtin_nontemporal_load(&w4[f0]);
        f32x4 c0 = __builtin_nontemporal_load(&x4[f0]);
        f32x4 a1 = __builtin_nontemporal_load(&w4[f0 + 256]);
        f32x4 c1 = __builtin_nontemporal_load(&x4[f0 + 256]);
        f32x4 a2 = __builtin_nontemporal_load(&w4[f0 + 512]);
        f32x4 c2 = __builtin_nontemporal_load(&x4[f0 + 512]);
        f32x4 a3 = __builtin_nontemporal_load(&w4[f0 + 768]);
        f32x4 c3 = __builtin_nontemporal_load(&x4[f0 + 768]);
#pragma unroll
        for (int p = 0; p < PASSES; ++p) {
            f32x4 an = (f32x4)(0.f);
            f32x4 cn = (f32x4)(0.f);
            if (p + 4 < PASSES) {             // compile-time after unroll
                an = __builtin_nontemporal_load(&w4[f0 + (long long)(p + 4) * 256]);
                cn = __builtin_nontemporal_load(&x4[f0 + (long long)(p + 4) * 256]);
            }
            __builtin_amdgcn_sched_barrier(0); // prefetch issued before consume
            double d = (double)a0.x * c0.x + (double)a0.y * c0.y
                     + (double)a0.z * c0.z + (double)a0.w * c0.w;
            d += __shfl_xor(d, 1, 64);         // d01 on q=0/1, d23 on q=2/3
            if ((q & 1) == 0)
                Qs[q >> 1][p * 64 + rsub] = d; // fire-and-forget ds_write_b64
            a0 = a1; c0 = c1;
            a1 = a2; c1 = c2;
            a2 = a3; c2 = c3;
            a3 = an; c3 = cn;
        }
    } else {
        for (int p = 0; p < PASSES; ++p) {
            long long row = base + (long long)p * 64 + rsub;
            double d = 0.0;
            if (row < (long long)nrows) {
                long long f = row * 4 + q;
                f32x4 a = w4[f], c = x4[f];
                d = (double)a.x * c.x + (double)a.y * c.y
                  + (double)a.z * c.z + (double)a.w * c.w;
            }
            d += __shfl_xor(d, 1, 64);
            if ((q & 1) == 0 && row < (long long)nrows)
                Qs[q >> 1][p * 64 + rsub] = d;
        }
    }
    __syncthreads();

    // ---- Phase B: combine pairs; R stays in registers ----
    long long g0 = base + (long long)tid * LPT;
    long long rem = (long long)nrows - g0;
    int len = rem >= LPT ? LPT : (rem > 0 ? (int)rem : 0);

    float rv[LPT];
#pragma unroll
    for (int r = 0; r < LPT; ++r) {
        int lr = tid * LPT + r;
        rv[r] = (float)(Qs[0][lr] + Qs[1][lr]); // (d0+d1)+(d2+d3) order
    }

    // ---- Phase C: thread aggregate + block scan; publish block aggregate ----
    double m = 1.0, sA = 0.0, sB = 0.0;
    for (int k = 0; k < len; ++k) {
        double r = (double)rv[k];
        sA = D_C * sA + D_ETA * r;
        sB = D_C * sB + D_ETA * (r * r);
        m *= D_C;
    }
    block_scan(m, sA, sB, mS, aS, bS);
    if (tid == BLOCK - 1) {
        pub_d(&aggM[b], m);
        pub_d(&aggA[b], sA);
        pub_d(&aggB[b], sB);
        __hip_atomic_store(&flags[b], 1, __ATOMIC_RELEASE, __HIP_MEMORY_SCOPE_AGENT);
    }
    double em = 1.0, ea = 0.0, eb = 0.0;
    if (tid > 0) { em = mS[tid - 1]; ea = aS[tid - 1]; eb = bS[tid - 1]; }
    __syncthreads();  // mS/aS/bS reused by the lookback scan

    // ---- Phase D: decoupled lookback over predecessor aggregates ----
    // Spins only on blocks with lower blockIdx (dispatched earlier).
    double Astart, Bstart;
    {
        const int H = b;
        const int K = (H + BLOCK - 1) / BLOCK;   // 0 when b==0
        double cm = 1.0, ca = 0.0, cb = 0.0;
        int s0 = tid * K;
        int s1 = s0 + K; if (s1 > H) s1 = H;
        for (int g = s0; g < s1; ++g) {
            while (__hip_atomic_load(&flags[g], __ATOMIC_ACQUIRE,
                                     __HIP_MEMORY_SCOPE_AGENT) == 0)
                __builtin_amdgcn_s_sleep(2);
            double mg = rd_d(&aggM[g]), ag = rd_d(&aggA[g]), bg = rd_d(&aggB[g]);
            ca = mg * ca + ag;
            cb = mg * cb + bg;
            cm *= mg;
        }
        block_scan(cm, ca, cb, mS, aS, bS);
        double M  = mS[BLOCK - 1];
        double SA = aS[BLOCK - 1];
        double SB = bS[BLOCK - 1];
        Astart = SA;                 // M*0 + SA
        Bstart = M * D_EPS + SB;
    }

    // ---- Phase E: per-thread entry state ----
    double A = em * Astart + ea;
    double B = em * Bstart + eb;

    // ---- Phase F: replay + D sum ----
    double dsum = 0.0;
    for (int k = 0; k < len; ++k) {
        double r = (double)rv[k];
        double dA = D_ETA * (r - A);
        double dB = D_ETA * (r * r - B);
        double var = B - A * A;
        if (var < D_EPS) var = D_EPS;
        double denom = var * sqrt(var);
        dsum += (B * dA - 0.5 * A * dB) / denom;
        A += dA;
        B += dB;
    }
#pragma unroll
    for (int off = 32; off > 0; off >>= 1) dsum += __shfl_down(dsum, off, 64);
    if ((tid & 63) == 0) wsum[tid >> 6] = dsum;
    __syncthreads();
    if (tid == 0) {
        double tot = wsum[0] + wsum[1] + wsum[2] + wsum[3];
        pub_d(&bsum[b], tot);
        int prev = __hip_atomic_fetch_add(done, 1, __ATOMIC_ACQ_REL,
                                          __HIP_MEMORY_SCOPE_AGENT);
        amLast = (prev == nb - 1);
    }
    __syncthreads();

    // ---- Phase G: last block reduces (k5 verbatim order: deterministic) ----
    if (amLast) {
        double s = 0.0;
        for (int i = tid; i < nb; i += BLOCK) s += rd_d(&bsum[i]);
#pragma unroll
        for (int off = 32; off > 0; off >>= 1) s += __shfl_down(s, off, 64);
        if ((tid & 63) == 0) wsum[tid >> 6] = s;
        __syncthreads();
        if (tid == 0)
            out[0] = (float)(-(wsum[0] + wsum[1] + wsum[2] + wsum[3])
                             / (double)nrows);
    }
}

extern "C" void kernel_launch(void* const* d_in, const int* in_sizes, int n_in,
                              void* d_out, int out_size, void* d_ws, size_t ws_size,
                              hipStream_t stream)
{
    const float* w = (const float*)d_in[0];
    const float* x = (const float*)d_in[1];
    int nrows = in_sizes[0] / 16;
    int nb = (nrows + CHUNK - 1) / CHUNK;

    char* ws = (char*)d_ws;
    double* aggM = (double*)(ws + 64);
    double* aggA = aggM + nb;
    double* aggB = aggA + nb;
    double* bsum = aggB + nb;
    int*    flags = (int*)(bsum + nb);     // nb flags + 1 done counter
    int*    done  = flags + nb;

    size_t need = 64 + (size_t)4 * nb * sizeof(double) + (size_t)(nb + 1) * sizeof(int);
    if (ws_size < need) return;  // harness provides 512 MB; ~71 KB needed

    int initBlocks = (nb + 1 + BLOCK - 1) / BLOCK;
    k_init<<<initBlocks, BLOCK, 0, stream>>>(flags, nb + 1);
    k_all<<<nb, BLOCK, 0, stream>>>(w, x, nrows, nb,
                                    aggM, aggA, aggB, flags, bsum, done,
                                    (float*)d_out);
}